// Round 4
// baseline (601.825 us; speedup 1.0000x reference)
//
#include <hip/hip_runtime.h>

// MoE: B=4,S=2048 -> T=8192 tokens, D=1024, H=2048, O=1024, E=8, K=2
#define T_TOKENS 8192
#define D_DIM 1024
#define H_DIM 2048
#define O_DIM 1024
#define E_NUM 8
#define NPAIR 16384   // T_TOKENS * 2
#define GT_MAX 72     // >= max possible sum ceil(ne/256) = 64 + 8

typedef unsigned short u16;
typedef __bf16 bf16x8 __attribute__((ext_vector_type(8)));
typedef float f32x4 __attribute__((ext_vector_type(4)));

// ---- scheduling / wait primitives (8-phase template, learn_hip m201) ----
#define VMC(IMM)                                                   \
  __builtin_amdgcn_sched_barrier(0);                               \
  asm volatile("s_waitcnt vmcnt(" #IMM ")" ::: "memory")
#define LGKM0                                                      \
  asm volatile("s_waitcnt lgkmcnt(0)" ::: "memory");               \
  __builtin_amdgcn_sched_barrier(0)   /* rule #18 */
#define SB0 __builtin_amdgcn_sched_barrier(0)

__device__ __forceinline__ void barsync() {
  asm volatile("" ::: "memory");
  __builtin_amdgcn_s_barrier();
  __builtin_amdgcn_sched_barrier(0);
}

// inline-asm ds_read_b128: opaque to SIInsertWaitcnts' LDS-DMA tracking, so
// no compiler vmcnt can attach; our explicit VMC/LGKM0 protocol is the wait.
#define DSR(dst, base, IMM)                                        \
  asm volatile("ds_read_b128 %0, %1 offset:" #IMM                  \
               : "=v"(dst) : "v"(base))

__device__ __forceinline__ unsigned ldsaddr(const u16* p) {
  return (unsigned)(size_t)(const __attribute__((address_space(3))) u16*)p;
}

__device__ inline u16 f2bf(float f) {
  union { float f; unsigned u; } v; v.f = f;
  unsigned r = v.u + 0x7FFFu + ((v.u >> 16) & 1u);   // RNE
  return (u16)(r >> 16);
}

// async 16B global -> LDS (deposits at wave-uniform base + lane*16)
__device__ __forceinline__ void gload16(const u16* g, u16* l) {
  __builtin_amdgcn_global_load_lds((const __attribute__((address_space(1))) void*)g,
                                   (__attribute__((address_space(3))) void*)l, 16, 0, 0);
}

// ---------------- prep: transpose+cast weights: [E,R,C] f32 -> [E,C,R] bf16 ----
__global__ void transpose_cvt_kernel(const float* __restrict__ w, u16* __restrict__ wt,
                                     int R, int C) {
  __shared__ float tile[32][33];
  int e = blockIdx.z;
  int c0 = blockIdx.x * 32, r0 = blockIdx.y * 32;
  const float* wp = w + (size_t)e * R * C;
  u16* wtp = wt + (size_t)e * R * C;
  int tx = threadIdx.x, ty = threadIdx.y;  // (32,8)
  #pragma unroll
  for (int j = 0; j < 32; j += 8)
    tile[ty + j][tx] = wp[(size_t)(r0 + ty + j) * C + c0 + tx];
  __syncthreads();
  #pragma unroll
  for (int j = 0; j < 32; j += 8)
    wtp[(size_t)(c0 + ty + j) * R + r0 + tx] = f2bf(tile[tx][ty + j]);
}

// ---------------- gating + x->bf16 cast fused (NO atomics) ----------------
__global__ void gate_kernel(const float* __restrict__ x, const float* __restrict__ gw,
                            const float* __restrict__ gb, int* __restrict__ topk_idx,
                            float* __restrict__ topk_val, u16* __restrict__ xb) {
  int t = blockIdx.x * 4 + (threadIdx.x >> 6);   // one wave per token
  int lane = threadIdx.x & 63;
  const float4* xr4 = (const float4*)(x + (size_t)t * D_DIM);
  const float4* gw4 = (const float4*)gw;
  u16* xbr = xb + (size_t)t * D_DIM;
  float acc[E_NUM];
  #pragma unroll
  for (int e = 0; e < E_NUM; e++) acc[e] = 0.f;
  #pragma unroll
  for (int it = 0; it < D_DIM / 256; ++it) {
    float4 xv = xr4[it * 64 + lane];
    ushort4 o;
    o.x = f2bf(xv.x); o.y = f2bf(xv.y); o.z = f2bf(xv.z); o.w = f2bf(xv.w);
    *(ushort4*)(xbr + (it * 64 + lane) * 4) = o;
    #pragma unroll
    for (int e = 0; e < E_NUM; e++) {
      float4 wv = gw4[e * (D_DIM / 4) + it * 64 + lane];
      acc[e] += xv.x * wv.x + xv.y * wv.y + xv.z * wv.z + xv.w * wv.w;
    }
  }
  #pragma unroll
  for (int e = 0; e < E_NUM; e++) {
    #pragma unroll
    for (int o = 32; o > 0; o >>= 1) acc[e] += __shfl_down(acc[e], o);
  }
  if (lane == 0) {
    float l[E_NUM], mx = -1e30f;
    #pragma unroll
    for (int e = 0; e < E_NUM; e++) { l[e] = acc[e] + gb[e]; mx = fmaxf(mx, l[e]); }
    float p[E_NUM], s = 0.f;
    #pragma unroll
    for (int e = 0; e < E_NUM; e++) { p[e] = expf(l[e] - mx); s += p[e]; }
    float inv = 1.f / s;
    int i1 = 0;
    #pragma unroll
    for (int e = 1; e < E_NUM; e++) if (p[e] > p[i1]) i1 = e;   // strict >: lowest idx on tie
    int i2 = (i1 == 0) ? 1 : 0;
    #pragma unroll
    for (int e = 0; e < E_NUM; e++) if (e != i1 && e != i2 && p[e] > p[i2]) i2 = e;
    topk_idx[t * 2] = i1;     topk_idx[t * 2 + 1] = i2;
    topk_val[t * 2] = p[i1] * inv; topk_val[t * 2 + 1] = p[i2] * inv;
  }
}

// ---------------- histogram + scan + tile table (BM=256): 1 block ----------------
__global__ void histscan_kernel(const int* __restrict__ topk_idx,
                                int* __restrict__ counts, int* __restrict__ eoff,
                                int* __restrict__ nblk, int* __restrict__ tbl_e,
                                int* __restrict__ tbl_m0) {
  __shared__ int wh[4][E_NUM];
  int tid = threadIdx.x;           // 256 threads
  int lane = tid & 63, wave = tid >> 6;
  int myc = 0;
  for (int i = tid; i < NPAIR; i += 256) {
    int e = topk_idx[i];
    #pragma unroll
    for (int ee = 0; ee < E_NUM; ee++) {
      unsigned long long m = __ballot(e == ee);
      if (lane == ee) myc += __popcll(m);
    }
  }
  if (lane < E_NUM) wh[wave][lane] = myc;
  __syncthreads();
  if (tid == 0) {
    int s = 0, cl[E_NUM];
    for (int e = 0; e < E_NUM; e++) {
      int c = wh[0][e] + wh[1][e] + wh[2][e] + wh[3][e];
      counts[e] = c;
      cl[e] = c;
      eoff[e] = s;
      s += c;
    }
    eoff[E_NUM] = s;
    int nb = 0;
    for (int e = 0; e < E_NUM; e++)
      for (int m0 = 0; m0 < cl[e]; m0 += 256) { tbl_e[nb] = e; tbl_m0[nb] = m0; nb++; }
    nblk[0] = nb;   // <= 72
  }
}

// ---------------- scatter: per-block LDS agg + padded global cursors ----------------
__global__ void scatter_kernel(const int* __restrict__ topk_idx, const float* __restrict__ topk_val,
                               const int* __restrict__ eoff, int* __restrict__ cursor_pad,
                               int* __restrict__ pair_token, float* __restrict__ pair_gate) {
  __shared__ int lhist[E_NUM];
  __shared__ int lbase[E_NUM];
  int tid = threadIdx.x;
  int t = blockIdx.x * 256 + tid;
  if (tid < E_NUM) lhist[tid] = 0;
  __syncthreads();
  int e0 = topk_idx[t * 2], e1 = topk_idx[t * 2 + 1];
  int r0 = atomicAdd(&lhist[e0], 1);
  int r1 = atomicAdd(&lhist[e1], 1);
  __syncthreads();
  if (tid < E_NUM) lbase[tid] = eoff[tid] + atomicAdd(&cursor_pad[tid * 32], lhist[tid]);
  __syncthreads();
  int p0 = lbase[e0] + r0;
  int p1 = lbase[e1] + r1;
  pair_token[p0] = t; pair_gate[p0] = topk_val[t * 2];
  pair_token[p1] = t; pair_gate[p1] = topk_val[t * 2 + 1];
}

// ===================== 256x256 8-phase GEMM core (m201 port) =====================
// BM=BN=256, BK=64, 8 waves (2M x 4N), 512 thr, 128 KiB LDS (2 dbuf x A,B 32KB).
// Per K-tile t (buf t&1): 4 phases, each {asm ds_reads ∥ stage 1 half-tile of
// t+1 -> barrier -> lgkmcnt(0)+sched_barrier -> setprio(1) 16 MFMA setprio(0)
// -> barrier}. Counted vmcnt ONCE per K-tile: at P0, after issuing the first
// next-half stage, VMC(2) retires exactly tile t's 8 deposits while keeping
// the new stage in flight. vmcnt(0) only in the final tile. Loads thus span
// barriers (T4); phase role-split makes setprio pay (T5).
// LDS layout: 128B rows (64 u16), 16B slot g of row r at phys slot g^(r&7);
// gload16 deposit is linear (row=lane>>3, slot=lane&7) with pre-inverse-
// swizzled source addrs; ds_read slot = (kk*4+quad)^(lrow&7) -> 2 lanes/bank.
// Fragments: per wave acc[8][4] (M-frags 8, N-frags 4); bf[4][2] read at P0;
// af pair per phase via offset-imm asm reads (frag stride 2048B).

#define MFMA16(I0)                                                              \
  __builtin_amdgcn_s_setprio(1);                                                \
  _Pragma("unroll")                                                             \
  for (int j = 0; j < 4; ++j) {                                                 \
    acc[I0][j]     = __builtin_amdgcn_mfma_f32_16x16x32_bf16(af[0][0], bf[j][0], acc[I0][j], 0, 0, 0);     \
    acc[I0][j]     = __builtin_amdgcn_mfma_f32_16x16x32_bf16(af[0][1], bf[j][1], acc[I0][j], 0, 0, 0);     \
    acc[I0 + 1][j] = __builtin_amdgcn_mfma_f32_16x16x32_bf16(af[1][0], bf[j][0], acc[I0 + 1][j], 0, 0, 0); \
    acc[I0 + 1][j] = __builtin_amdgcn_mfma_f32_16x16x32_bf16(af[1][1], bf[j][1], acc[I0 + 1][j], 0, 0, 0); \
  }                                                                             \
  __builtin_amdgcn_s_setprio(0)

#define READS_P0                                                                \
  DSR(bf[0][0], bB0, 0); DSR(bf[1][0], bB0, 2048); DSR(bf[2][0], bB0, 4096); DSR(bf[3][0], bB0, 6144); \
  DSR(bf[0][1], bB1, 0); DSR(bf[1][1], bB1, 2048); DSR(bf[2][1], bB1, 4096); DSR(bf[3][1], bB1, 6144); \
  DSR(af[0][0], aA0, 0); DSR(af[1][0], aA0, 2048); DSR(af[0][1], aA1, 0); DSR(af[1][1], aA1, 2048)

#define READS_AF(O0, O1)                                                        \
  DSR(af[0][0], aA0, O0); DSR(af[1][0], aA0, O1);                               \
  DSR(af[0][1], aA1, O0); DSR(af[1][1], aA1, O1)

#define STAGE_A(ARR, H, K1)                                                     \
  gload16(aptrA[H][0] + (K1), &ARR[(H) * 8192 + (wid * 16 + 0) * 64]);          \
  gload16(aptrA[H][1] + (K1), &ARR[(H) * 8192 + (wid * 16 + 8) * 64])
#define STAGE_B(ARR, H, K1)                                                     \
  gload16(bptrB[H][0] + (K1), &ARR[(H) * 8192 + (wid * 16 + 0) * 64]);          \
  gload16(bptrB[H][1] + (K1), &ARR[(H) * 8192 + (wid * 16 + 8) * 64])

// one K-tile: cur bases (u32), next arrays, k-offset of tile t+1, vmcnt imm, stage?
#define TILE(AcB, BcB, AN, BN, K1, VMIMM, DOSTAGE)                              \
  {                                                                             \
    unsigned aA0 = (AcB) + aoffs0, aA1 = (AcB) + aoffs1;                        \
    unsigned bB0 = (BcB) + boffs0, bB1 = (BcB) + boffs1;                        \
    /* P0 */                                                                    \
    if (DOSTAGE) { STAGE_A(AN, 0, K1); }                                        \
    VMC(VMIMM);                                                                 \
    barsync();                                                                  \
    READS_P0; LGKM0; MFMA16(0); barsync();                                      \
    /* P1 */                                                                    \
    READS_AF(4096, 6144);                                                       \
    if (DOSTAGE) { STAGE_A(AN, 1, K1); } SB0;                                   \
    barsync(); LGKM0; MFMA16(2); barsync();                                     \
    /* P2 */                                                                    \
    READS_AF(8192, 10240);                                                      \
    if (DOSTAGE) { STAGE_B(BN, 0, K1); } SB0;                                   \
    barsync(); LGKM0; MFMA16(4); barsync();                                     \
    /* P3 */                                                                    \
    READS_AF(12288, 14336);                                                     \
    if (DOSTAGE) { STAGE_B(BN, 1, K1); } SB0;                                   \
    barsync(); LGKM0; MFMA16(6); barsync();                                     \
  }

#define GEMM_CORE_DECLS                                                         \
  __shared__ __align__(16) u16 A0s[16384], B0s[16384], A1s[16384], B1s[16384];  \
  const int tid = threadIdx.x;                                                  \
  const int wid = tid >> 6;                                                     \
  const int lane = tid & 63;                                                    \
  const int wm = wid & 1;                                                       \
  const int wn = wid >> 1;                                                      \
  const unsigned lrow = lane & 15;                                              \
  const unsigned quad = lane >> 4;                                              \
  const unsigned A0b = ldsaddr(A0s), B0b = ldsaddr(B0s);                        \
  const unsigned A1b = ldsaddr(A1s), B1b = ldsaddr(B1s);                        \
  const unsigned aoffs0 = ((wm * 128 + lrow) * 64 + ((quad ^ (lrow & 7)) * 8)) * 2;       \
  const unsigned aoffs1 = ((wm * 128 + lrow) * 64 + (((4 + quad) ^ (lrow & 7)) * 8)) * 2; \
  const unsigned boffs0 = ((wn * 64 + lrow) * 64 + ((quad ^ (lrow & 7)) * 8)) * 2;        \
  const unsigned boffs1 = ((wn * 64 + lrow) * 64 + (((4 + quad) ^ (lrow & 7)) * 8)) * 2;  \
  f32x4 acc[8][4] = {};                                                         \
  bf16x8 af[2][2], bf[4][2];

// ---------------- GEMM1: h = relu(x[tok] @ w1[e] + b1[e]) -> hbuf bf16 ----------------
__global__ __launch_bounds__(512, 2) void gemm1_kernel(
    const u16* __restrict__ xb, const u16* __restrict__ w1t, const float* __restrict__ b1,
    const int* __restrict__ pair_token, const int* __restrict__ eoff,
    const int* __restrict__ ecnt, const int* __restrict__ nblk,
    const int* __restrict__ tbl_e, const int* __restrict__ tbl_m0,
    u16* __restrict__ hbuf) {
  // XCD-chunk swizzle over nwg = 8 * GT_MAX = 576
  int lin = blockIdx.x;
  int swz = (lin & 7) * (8 * GT_MAX / 8) + (lin >> 3);
  const int bx = swz & 7;
  const int yb = swz >> 3;
  if (yb >= nblk[0]) return;
  const int e = tbl_e[yb];
  const int m0t = tbl_m0[yb];
  const int ne = ecnt[e];
  const int off = eoff[e];
  const int n0 = bx * 256;

  GEMM_CORE_DECLS;

  // staging source ptrs (inverse-swizzled): [half][issue]
  const u16* aptrA[2][2]; const u16* bptrB[2][2];
  #pragma unroll
  for (int h = 0; h < 2; h++)
    #pragma unroll
    for (int j = 0; j < 2; j++) {
      int rw = h * 128 + wid * 16 + j * 8 + (lane >> 3);
      int sl = (lane & 7) ^ (rw & 7);
      int gm = m0t + rw;
      int tok = (gm < ne) ? pair_token[off + gm] : 0;
      aptrA[h][j] = xb + (size_t)tok * D_DIM + sl * 8;
      bptrB[h][j] = w1t + ((size_t)e * H_DIM + (n0 + rw)) * D_DIM + sl * 8;
    }

  // NT = D_DIM/64 = 16 K-tiles
  STAGE_A(A0s, 0, 0); STAGE_A(A0s, 1, 0); STAGE_B(B0s, 0, 0); STAGE_B(B0s, 1, 0);
  #pragma unroll 1
  for (int tt = 0; tt < 14; tt += 2) {
    TILE(A0b, B0b, A1s, B1s, (tt + 1) * 64, 2, true);
    TILE(A1b, B1b, A0s, B0s, (tt + 2) * 64, 2, true);
  }
  TILE(A0b, B0b, A1s, B1s, 15 * 64, 2, true);   // tile 14
  TILE(A1b, B1b, A0s, B0s, 0, 0, false);        // tile 15: drain

  // epilogue: +b1, relu, bf16 store. C/D: col=lrow, row=quad*4+reg
  #pragma unroll
  for (int i = 0; i < 8; i++) {
    #pragma unroll
    for (int r = 0; r < 4; r++) {
      int m = wm * 128 + i * 16 + quad * 4 + r;
      int gm = m0t + m;
      if (gm >= ne) continue;
      size_t rowbase = (size_t)(off + gm) * H_DIM;
      #pragma unroll
      for (int j = 0; j < 4; j++) {
        int n = n0 + wn * 64 + j * 16 + lrow;
        float v = acc[i][j][r] + b1[e * H_DIM + n];
        v = v > 0.f ? v : 0.f;
        hbuf[rowbase + n] = f2bf(v);
      }
    }
  }
}

// ---------------- GEMM2: out[tok] += gate * (h @ w2[e] + b2[e]), split-K=2 ----------------
__global__ __launch_bounds__(512, 2) void gemm2_kernel(
    const u16* __restrict__ hbuf, const u16* __restrict__ w2t, const float* __restrict__ b2,
    const int* __restrict__ pair_token, const float* __restrict__ pair_gate,
    const int* __restrict__ eoff, const int* __restrict__ ecnt,
    const int* __restrict__ nblk, const int* __restrict__ tbl_e,
    const int* __restrict__ tbl_m0, float* __restrict__ out) {
  // XCD-chunk swizzle over nwg = 4 * 2 * GT_MAX = 576
  int lin = blockIdx.x;
  int swz = (lin & 7) * (8 * GT_MAX / 8) + (lin >> 3);
  const int bx = swz & 3;
  const int ks = (swz >> 2) & 1;            // K-split half
  const int yb = swz >> 3;
  if (yb >= nblk[0]) return;
  const int e = tbl_e[yb];
  const int m0t = tbl_m0[yb];
  const int ne = ecnt[e];
  const int off = eoff[e];
  const int n0 = bx * 256;

  GEMM_CORE_DECLS;

  const u16* aptrA[2][2]; const u16* bptrB[2][2];
  #pragma unroll
  for (int h = 0; h < 2; h++)
    #pragma unroll
    for (int j = 0; j < 2; j++) {
      int rw = h * 128 + wid * 16 + j * 8 + (lane >> 3);
      int sl = (lane & 7) ^ (rw & 7);
      // hbuf has 256 slack rows past NPAIR; out-of-range rows discarded in epilogue
      aptrA[h][j] = hbuf + (size_t)(off + m0t + rw) * H_DIM + ks * 1024 + sl * 8;
      bptrB[h][j] = w2t + ((size_t)e * O_DIM + (n0 + rw)) * H_DIM + ks * 1024 + sl * 8;
    }

  // NT = (H_DIM/2)/64 = 16 K-tiles per split half
  STAGE_A(A0s, 0, 0); STAGE_A(A0s, 1, 0); STAGE_B(B0s, 0, 0); STAGE_B(B0s, 1, 0);
  #pragma unroll 1
  for (int tt = 0; tt < 14; tt += 2) {
    TILE(A0b, B0b, A1s, B1s, (tt + 1) * 64, 2, true);
    TILE(A1b, B1b, A0s, B0s, (tt + 2) * 64, 2, true);
  }
  TILE(A0b, B0b, A1s, B1s, 15 * 64, 2, true);   // tile 14
  TILE(A1b, B1b, A0s, B0s, 0, 0, false);        // tile 15: drain

  #pragma unroll
  for (int i = 0; i < 8; i++) {
    #pragma unroll
    for (int r = 0; r < 4; r++) {
      int m = wm * 128 + i * 16 + quad * 4 + r;
      int gm = m0t + m;
      if (gm >= ne) continue;
      int pair = off + gm;
      int tok = pair_token[pair];
      float g = pair_gate[pair];
      #pragma unroll
      for (int j = 0; j < 4; j++) {
        int n = n0 + wn * 64 + j * 16 + lrow;
        float v = (acc[i][j][r] + (ks ? 0.f : b2[e * O_DIM + n])) * g;
        atomicAdd(&out[(size_t)tok * O_DIM + n], v);
      }
    }
  }
}

extern "C" void kernel_launch(void* const* d_in, const int* in_sizes, int n_in,
                              void* d_out, int out_size, void* d_ws, size_t ws_size,
                              hipStream_t stream) {
  const float* x  = (const float*)d_in[0];
  const float* gw = (const float*)d_in[1];
  const float* gb = (const float*)d_in[2];
  const float* w1 = (const float*)d_in[3];
  const float* b1 = (const float*)d_in[4];
  const float* w2 = (const float*)d_in[5];
  const float* b2 = (const float*)d_in[6];
  float* out = (float*)d_out;

  char* ws = (char*)d_ws;
  size_t off = 0;
  auto take = [&](size_t bytes) -> char* {
    char* p = ws + off;
    off = (off + bytes + 255) & ~(size_t)255;
    return p;
  };
  int*   meta       = (int*)take(4096);  // cursor_pad[256] | counts[8] | eoff[9] | nblk | tbl_e[72] | tbl_m0[72]
  int*   cursor_pad = meta;
  int*   counts     = meta + 256;
  int*   eoff       = meta + 264;
  int*   nblk       = meta + 273;
  int*   tbl_e      = meta + 274;
  int*   tbl_m0     = meta + 346;
  int*   topk_idx   = (int*)take((size_t)T_TOKENS * 2 * 4);
  float* topk_val   = (float*)take((size_t)T_TOKENS * 2 * 4);
  int*   pair_token = (int*)take((size_t)(NPAIR + 256) * 4);
  float* pair_gate  = (float*)take((size_t)(NPAIR + 256) * 4);
  u16*   xb         = (u16*)take((size_t)T_TOKENS * D_DIM * 2);
  u16*   w1t        = (u16*)take((size_t)E_NUM * D_DIM * H_DIM * 2);
  u16*   w2t        = (u16*)take((size_t)E_NUM * H_DIM * O_DIM * 2);
  u16*   hbuf       = (u16*)take((size_t)(NPAIR + 256) * H_DIM * 2);

  hipMemsetAsync(meta, 0, 4096, stream);
  hipMemsetAsync(out, 0, (size_t)T_TOKENS * O_DIM * 4, stream);

  transpose_cvt_kernel<<<dim3(H_DIM / 32, D_DIM / 32, E_NUM), dim3(32, 8), 0, stream>>>(w1, w1t, D_DIM, H_DIM);
  transpose_cvt_kernel<<<dim3(O_DIM / 32, H_DIM / 32, E_NUM), dim3(32, 8), 0, stream>>>(w2, w2t, H_DIM, O_DIM);
  gate_kernel<<<T_TOKENS / 4, 256, 0, stream>>>(x, gw, gb, topk_idx, topk_val, xb);
  histscan_kernel<<<1, 256, 0, stream>>>(topk_idx, counts, eoff, nblk, tbl_e, tbl_m0);
  scatter_kernel<<<T_TOKENS / 256, 256, 0, stream>>>(topk_idx, topk_val, eoff, cursor_pad, pair_token, pair_gate);
  gemm1_kernel<<<dim3(8 * GT_MAX), 512, 0, stream>>>(xb, w1t, b1, pair_token, eoff, counts, nblk, tbl_e, tbl_m0, hbuf);
  gemm2_kernel<<<dim3(8 * GT_MAX), 512, 0, stream>>>(hbuf, w2t, b2, pair_token, pair_gate, eoff, counts, nblk, tbl_e, tbl_m0, out);
}

// Round 5
// 451.531 us; speedup vs baseline: 1.3329x; 1.3329x over previous
//
#include <hip/hip_runtime.h>

// MoE: B=4,S=2048 -> T=8192 tokens, D=1024, H=2048, O=1024, E=8, K=2
#define T_TOKENS 8192
#define D_DIM 1024
#define H_DIM 2048
#define O_DIM 1024
#define E_NUM 8
#define NPAIR 16384   // T_TOKENS * 2
#define GY_MAX 136    // >= max possible sum ceil(ne/128) = 135

typedef unsigned short u16;
typedef __bf16 bf16x8 __attribute__((ext_vector_type(8)));
typedef float f32x4 __attribute__((ext_vector_type(4)));

// counted waitcnt: loads stay in flight across barriers; literal immediate.
#define VMCNT(n) asm volatile("s_waitcnt vmcnt(" #n ")" ::: "memory")

__device__ __forceinline__ void barsync() {
  asm volatile("" ::: "memory");
  __builtin_amdgcn_s_barrier();
  __builtin_amdgcn_sched_barrier(0);
}

__device__ inline u16 f2bf(float f) {
  union { float f; unsigned u; } v; v.f = f;
  unsigned r = v.u + 0x7FFFu + ((v.u >> 16) & 1u);   // RNE
  return (u16)(r >> 16);
}

// async 16B global -> LDS (deposits at wave-uniform base + lane*16)
__device__ __forceinline__ void gload16(const u16* g, u16* l) {
  __builtin_amdgcn_global_load_lds((const __attribute__((address_space(1))) void*)g,
                                   (__attribute__((address_space(3))) void*)l, 16, 0, 0);
}

// ---------------- prep: transpose+cast weights: [E,R,C] f32 -> [E,C,R] bf16 ----
__global__ void transpose_cvt_kernel(const float* __restrict__ w, u16* __restrict__ wt,
                                     int R, int C) {
  __shared__ float tile[32][33];
  int e = blockIdx.z;
  int c0 = blockIdx.x * 32, r0 = blockIdx.y * 32;
  const float* wp = w + (size_t)e * R * C;
  u16* wtp = wt + (size_t)e * R * C;
  int tx = threadIdx.x, ty = threadIdx.y;  // (32,8)
  #pragma unroll
  for (int j = 0; j < 32; j += 8)
    tile[ty + j][tx] = wp[(size_t)(r0 + ty + j) * C + c0 + tx];
  __syncthreads();
  #pragma unroll
  for (int j = 0; j < 32; j += 8)
    wtp[(size_t)(c0 + ty + j) * R + r0 + tx] = f2bf(tile[tx][ty + j]);
}

// ---------------- gating + x->bf16 cast fused (NO atomics) ----------------
__global__ void gate_kernel(const float* __restrict__ x, const float* __restrict__ gw,
                            const float* __restrict__ gb, int* __restrict__ topk_idx,
                            float* __restrict__ topk_val, u16* __restrict__ xb) {
  int t = blockIdx.x * 4 + (threadIdx.x >> 6);   // one wave per token
  int lane = threadIdx.x & 63;
  const float4* xr4 = (const float4*)(x + (size_t)t * D_DIM);
  const float4* gw4 = (const float4*)gw;
  u16* xbr = xb + (size_t)t * D_DIM;
  float acc[E_NUM];
  #pragma unroll
  for (int e = 0; e < E_NUM; e++) acc[e] = 0.f;
  #pragma unroll
  for (int it = 0; it < D_DIM / 256; ++it) {
    float4 xv = xr4[it * 64 + lane];
    ushort4 o;
    o.x = f2bf(xv.x); o.y = f2bf(xv.y); o.z = f2bf(xv.z); o.w = f2bf(xv.w);
    *(ushort4*)(xbr + (it * 64 + lane) * 4) = o;
    #pragma unroll
    for (int e = 0; e < E_NUM; e++) {
      float4 wv = gw4[e * (D_DIM / 4) + it * 64 + lane];
      acc[e] += xv.x * wv.x + xv.y * wv.y + xv.z * wv.z + xv.w * wv.w;
    }
  }
  #pragma unroll
  for (int e = 0; e < E_NUM; e++) {
    #pragma unroll
    for (int o = 32; o > 0; o >>= 1) acc[e] += __shfl_down(acc[e], o);
  }
  if (lane == 0) {
    float l[E_NUM], mx = -1e30f;
    #pragma unroll
    for (int e = 0; e < E_NUM; e++) { l[e] = acc[e] + gb[e]; mx = fmaxf(mx, l[e]); }
    float p[E_NUM], s = 0.f;
    #pragma unroll
    for (int e = 0; e < E_NUM; e++) { p[e] = expf(l[e] - mx); s += p[e]; }
    float inv = 1.f / s;
    int i1 = 0;
    #pragma unroll
    for (int e = 1; e < E_NUM; e++) if (p[e] > p[i1]) i1 = e;   // strict >: lowest idx on tie
    int i2 = (i1 == 0) ? 1 : 0;
    #pragma unroll
    for (int e = 0; e < E_NUM; e++) if (e != i1 && e != i2 && p[e] > p[i2]) i2 = e;
    topk_idx[t * 2] = i1;     topk_idx[t * 2 + 1] = i2;
    topk_val[t * 2] = p[i1] * inv; topk_val[t * 2 + 1] = p[i2] * inv;
  }
}

// ---------------- histogram + scan + tile table: 1 block ----------------
__global__ void histscan_kernel(const int* __restrict__ topk_idx,
                                int* __restrict__ counts, int* __restrict__ eoff,
                                int* __restrict__ nblk, int* __restrict__ tbl_e,
                                int* __restrict__ tbl_m0) {
  __shared__ int wh[4][E_NUM];
  int tid = threadIdx.x;           // 256 threads
  int lane = tid & 63, wave = tid >> 6;
  int myc = 0;                     // lane e (<8) accumulates count of expert e
  for (int i = tid; i < NPAIR; i += 256) {
    int e = topk_idx[i];
    #pragma unroll
    for (int ee = 0; ee < E_NUM; ee++) {
      unsigned long long m = __ballot(e == ee);
      if (lane == ee) myc += __popcll(m);
    }
  }
  if (lane < E_NUM) wh[wave][lane] = myc;
  __syncthreads();
  if (tid == 0) {
    int s = 0, cl[E_NUM];
    for (int e = 0; e < E_NUM; e++) {
      int c = wh[0][e] + wh[1][e] + wh[2][e] + wh[3][e];
      counts[e] = c;
      cl[e] = c;
      eoff[e] = s;
      s += c;
    }
    eoff[E_NUM] = s;
    // flattened M-tile table shared by gemm1/gemm2 (BM=128)
    int nb = 0;
    for (int e = 0; e < E_NUM; e++)
      for (int m0 = 0; m0 < cl[e]; m0 += 128) { tbl_e[nb] = e; tbl_m0[nb] = m0; nb++; }
    nblk[0] = nb;   // <= 135
  }
}

// ---------------- scatter: per-block LDS agg + padded global cursors --------
// also writes inv_pos[t*2 + slot] = pair position of token t's slot-th expert
__global__ void scatter_kernel(const int* __restrict__ topk_idx, const float* __restrict__ topk_val,
                               const int* __restrict__ eoff, int* __restrict__ cursor_pad,
                               int* __restrict__ pair_token, int* __restrict__ inv_pos) {
  __shared__ int lhist[E_NUM];
  __shared__ int lbase[E_NUM];
  int tid = threadIdx.x;
  int t = blockIdx.x * 256 + tid;
  if (tid < E_NUM) lhist[tid] = 0;
  __syncthreads();
  int e0 = topk_idx[t * 2], e1 = topk_idx[t * 2 + 1];
  int r0 = atomicAdd(&lhist[e0], 1);
  int r1 = atomicAdd(&lhist[e1], 1);
  __syncthreads();
  if (tid < E_NUM) lbase[tid] = eoff[tid] + atomicAdd(&cursor_pad[tid * 32], lhist[tid]);
  __syncthreads();
  int p0 = lbase[e0] + r0;
  int p1 = lbase[e1] + r1;
  pair_token[p0] = t;
  pair_token[p1] = t;
  inv_pos[t * 2] = p0;
  inv_pos[t * 2 + 1] = p1;
}

// ---------------- combine: out[t] = g0*obuf[p0] + g1*obuf[p1] (no atomics) ----
__global__ void combine_kernel(const float* __restrict__ obuf, const int* __restrict__ inv_pos,
                               const float* __restrict__ topk_val, float* __restrict__ out) {
  int t = blockIdx.x;
  int tid = threadIdx.x;            // 256 threads, float4 each -> 1024 floats
  int p0 = inv_pos[t * 2], p1 = inv_pos[t * 2 + 1];
  float g0 = topk_val[t * 2], g1 = topk_val[t * 2 + 1];
  const float4* a4 = (const float4*)(obuf + (size_t)p0 * O_DIM);
  const float4* b4 = (const float4*)(obuf + (size_t)p1 * O_DIM);
  float4 a = a4[tid], b = b4[tid];
  float4 r;
  r.x = g0 * a.x + g1 * b.x;
  r.y = g0 * a.y + g1 * b.y;
  r.z = g0 * a.z + g1 * b.z;
  r.w = g0 * a.w + g1 * b.w;
  ((float4*)(out + (size_t)t * O_DIM))[tid] = r;
}

// ===================== GEMM core structure (round-3, tied-best) =====================
// BK=32, TRIPLE-buffered, six distinct __shared__ arrays, static 3-phase unroll,
// counted VMCNT(8) keeps 2 tiles in flight across barriers.
// LDS layout: BK=32 rows (64B) pair-packed into 64 physical 128B rows with the
// XOR-involution (0 bank conflicts, verified rounds 0-3).

#define GEMM_DECLS                                                             \
  __shared__ __align__(16) u16 As0[4096], Bs0[4096], As1[4096], Bs1[4096],     \
      As2[4096], Bs2[4096];                                                    \
  const int tid = threadIdx.x;                                                 \
  const int wid = tid >> 6;                                                    \
  const int lane = tid & 63;                                                   \
  const int wm = (wid & 1) * 64;                                               \
  const int wn = (wid >> 1) * 64;                                              \
  const int lrow = lane & 15;                                                  \
  const int quad = lane >> 4;                                                  \
  f32x4 acc[4][4] = {};                                                        \
  auto STAGE = [&](u16* Ab, u16* Bb, int k0) {                                 \
    _Pragma("unroll")                                                          \
    for (int j = 0; j < 2; j++) {                                              \
      gload16(aptrA[j] + k0, Ab + (wid * 16 + j * 8) * 64);                    \
      gload16(bptrB[j] + k0, Bb + (wid * 16 + j * 8) * 64);                    \
    }                                                                          \
  };                                                                           \
  auto COMPUTE = [&](const u16* Ab, const u16* Bb) {                           \
    bf16x8 af[4], bfr[4];                                                      \
    _Pragma("unroll")                                                          \
    for (int i = 0; i < 4; i++) {                                              \
      int r = wm + i * 16 + lrow;                                              \
      int p = r >> 1;                                                          \
      int s = (((r & 1) << 2) | quad) ^ (p & 7);                               \
      af[i] = *(const bf16x8*)&Ab[p * 64 + s * 8];                             \
    }                                                                          \
    _Pragma("unroll")                                                          \
    for (int j = 0; j < 4; j++) {                                              \
      int r = wn + j * 16 + lrow;                                              \
      int p = r >> 1;                                                          \
      int s = (((r & 1) << 2) | quad) ^ (p & 7);                               \
      bfr[j] = *(const bf16x8*)&Bb[p * 64 + s * 8];                            \
    }                                                                          \
    __builtin_amdgcn_s_setprio(1);                                             \
    _Pragma("unroll")                                                          \
    for (int i = 0; i < 4; i++)                                                \
      _Pragma("unroll")                                                        \
      for (int j = 0; j < 4; j++)                                              \
        acc[i][j] = __builtin_amdgcn_mfma_f32_16x16x32_bf16(af[i], bfr[j],     \
                                                            acc[i][j], 0, 0, 0);\
    __builtin_amdgcn_s_setprio(0);                                             \
  }

// ---------------- GEMM1: h = relu(x[tok] @ w1[e] + b1[e]) -> hbuf bf16 ----------------
__global__ __launch_bounds__(256, 3) void gemm1_kernel(
    const u16* __restrict__ xb, const u16* __restrict__ w1t, const float* __restrict__ b1,
    const int* __restrict__ pair_token, const int* __restrict__ eoff,
    const int* __restrict__ ecnt, const int* __restrict__ nblk,
    const int* __restrict__ tbl_e, const int* __restrict__ tbl_m0,
    u16* __restrict__ hbuf) {
  // XCD-chunk swizzle over nwg = 16*GY_MAX = 2176 (chunk 272)
  int lin = blockIdx.y * 16 + blockIdx.x;
  int swz = (lin & 7) * (16 * GY_MAX / 8) + (lin >> 3);
  const int bx = swz & 15;
  const int yb = swz >> 4;
  if (yb >= nblk[0]) return;
  const int e = tbl_e[yb];
  const int m0t = tbl_m0[yb];
  const int ne = ecnt[e];
  const int off = eoff[e];
  const int n0 = bx * 128;

  // per-lane staging source addresses (inverse-swizzled), 2 issues each A,B
  const u16* aptrA[2]; const u16* bptrB[2];
  {
    const int wid_ = threadIdx.x >> 6, lane_ = threadIdx.x & 63;
    #pragma unroll
    for (int j = 0; j < 2; j++) {
      int p = wid_ * 16 + j * 8 + (lane_ >> 3);
      int u = (lane_ & 7) ^ (p & 7);
      int r = 2 * p + (u >> 2);
      int c = u & 3;
      int gm = m0t + r;
      int tok = (gm < ne) ? pair_token[off + gm] : 0;
      aptrA[j] = xb + (size_t)tok * D_DIM + c * 8;
      bptrB[j] = w1t + ((size_t)e * H_DIM + (n0 + r)) * D_DIM + c * 8;
    }
  }

  GEMM_DECLS;

  // NT = D_DIM/32 = 32 tiles
  STAGE(As0, Bs0, 0); STAGE(As1, Bs1, 32); STAGE(As2, Bs2, 64);
  #pragma unroll 1
  for (int t = 0; t <= 32 - 6; t += 3) {
    VMCNT(8); barsync(); COMPUTE(As0, Bs0); barsync(); STAGE(As0, Bs0, (t + 3) * 32);
    VMCNT(8); barsync(); COMPUTE(As1, Bs1); barsync(); STAGE(As1, Bs1, (t + 4) * 32);
    VMCNT(8); barsync(); COMPUTE(As2, Bs2); barsync(); STAGE(As2, Bs2, (t + 5) * 32);
  }
  // tail: phases 27..31 (buffers 0,1,2,0,1), stages for tiles 30,31
  VMCNT(8); barsync(); COMPUTE(As0, Bs0); barsync(); STAGE(As0, Bs0, 30 * 32);
  VMCNT(8); barsync(); COMPUTE(As1, Bs1); barsync(); STAGE(As1, Bs1, 31 * 32);
  VMCNT(8); barsync(); COMPUTE(As2, Bs2);
  VMCNT(4); barsync(); COMPUTE(As0, Bs0);
  VMCNT(0); barsync(); COMPUTE(As1, Bs1);

  // epilogue: +b1, relu, bf16 store. C/D: col=lane&15, row=quad*4+reg
  #pragma unroll
  for (int i = 0; i < 4; i++) {
    #pragma unroll
    for (int r = 0; r < 4; r++) {
      int m = wm + i * 16 + quad * 4 + r;
      int gm = m0t + m;
      if (gm >= ne) continue;
      size_t rowbase = (size_t)(off + gm) * H_DIM;
      #pragma unroll
      for (int j = 0; j < 4; j++) {
        int n = n0 + wn + j * 16 + lrow;
        float v = acc[i][j][r] + b1[e * H_DIM + n];
        v = v > 0.f ? v : 0.f;
        hbuf[rowbase + n] = f2bf(v);
      }
    }
  }
}

// ---------------- GEMM2: obuf[pair] = h[pair] @ w2[e] + b2[e] (plain stores) ----
__global__ __launch_bounds__(256, 3) void gemm2_kernel(
    const u16* __restrict__ hbuf, const u16* __restrict__ w2t, const float* __restrict__ b2,
    const int* __restrict__ eoff, const int* __restrict__ ecnt,
    const int* __restrict__ nblk, const int* __restrict__ tbl_e,
    const int* __restrict__ tbl_m0, float* __restrict__ obuf) {
  // XCD-chunk swizzle over nwg = 8*GY_MAX = 1088 (chunk 136)
  int lin = blockIdx.y * 8 + blockIdx.x;
  int swz = (lin & 7) * (8 * GY_MAX / 8) + (lin >> 3);
  const int bx = swz & 7;
  const int yb = swz >> 3;
  if (yb >= nblk[0]) return;
  const int e = tbl_e[yb];
  const int m0t = tbl_m0[yb];
  const int ne = ecnt[e];
  const int off = eoff[e];
  const int n0 = bx * 128;

  const u16* aptrA[2]; const u16* bptrB[2];
  {
    const int wid_ = threadIdx.x >> 6, lane_ = threadIdx.x & 63;
    #pragma unroll
    for (int j = 0; j < 2; j++) {
      int p = wid_ * 16 + j * 8 + (lane_ >> 3);
      int u = (lane_ & 7) ^ (p & 7);
      int r = 2 * p + (u >> 2);
      int c = u & 3;
      // hbuf has 128 slack rows past NPAIR; out-of-range rows discarded in epilogue
      aptrA[j] = hbuf + (size_t)(off + m0t + r) * H_DIM + c * 8;
      bptrB[j] = w2t + ((size_t)e * O_DIM + (n0 + r)) * H_DIM + c * 8;
    }
  }

  GEMM_DECLS;

  // NT = H_DIM/32 = 64 tiles
  STAGE(As0, Bs0, 0); STAGE(As1, Bs1, 32); STAGE(As2, Bs2, 64);
  #pragma unroll 1
  for (int t = 0; t <= 64 - 6; t += 3) {
    VMCNT(8); barsync(); COMPUTE(As0, Bs0); barsync(); STAGE(As0, Bs0, (t + 3) * 32);
    VMCNT(8); barsync(); COMPUTE(As1, Bs1); barsync(); STAGE(As1, Bs1, (t + 4) * 32);
    VMCNT(8); barsync(); COMPUTE(As2, Bs2); barsync(); STAGE(As2, Bs2, (t + 5) * 32);
  }
  // tail: phases 60..63 (buffers 0,1,2,0), stage for tile 63
  VMCNT(8); barsync(); COMPUTE(As0, Bs0); barsync(); STAGE(As0, Bs0, 63 * 32);
  VMCNT(8); barsync(); COMPUTE(As1, Bs1);
  VMCNT(4); barsync(); COMPUTE(As2, Bs2);
  VMCNT(0); barsync(); COMPUTE(As0, Bs0);

  // epilogue: +b2, plain f32 store into private pair row (NO atomics;
  // gate weighting + token reduction happen in combine_kernel)
  #pragma unroll
  for (int i = 0; i < 4; i++) {
    #pragma unroll
    for (int r = 0; r < 4; r++) {
      int m = wm + i * 16 + quad * 4 + r;
      int gm = m0t + m;
      if (gm >= ne) continue;
      size_t rowbase = (size_t)(off + gm) * O_DIM;
      #pragma unroll
      for (int j = 0; j < 4; j++) {
        int n = n0 + wn + j * 16 + lrow;
        obuf[rowbase + n] = acc[i][j][r] + b2[e * O_DIM + n];
      }
    }
  }
}

extern "C" void kernel_launch(void* const* d_in, const int* in_sizes, int n_in,
                              void* d_out, int out_size, void* d_ws, size_t ws_size,
                              hipStream_t stream) {
  const float* x  = (const float*)d_in[0];
  const float* gw = (const float*)d_in[1];
  const float* gb = (const float*)d_in[2];
  const float* w1 = (const float*)d_in[3];
  const float* b1 = (const float*)d_in[4];
  const float* w2 = (const float*)d_in[5];
  const float* b2 = (const float*)d_in[6];
  float* out = (float*)d_out;

  char* ws = (char*)d_ws;
  size_t off = 0;
  auto take = [&](size_t bytes) -> char* {
    char* p = ws + off;
    off = (off + bytes + 255) & ~(size_t)255;
    return p;
  };
  int*   meta       = (int*)take(4096);  // cursor_pad[256] | counts[8] | eoff[9] | nblk | tbl_e[136] | tbl_m0[136]
  int*   cursor_pad = meta;
  int*   counts     = meta + 256;
  int*   eoff       = meta + 264;
  int*   nblk       = meta + 273;
  int*   tbl_e      = meta + 274;
  int*   tbl_m0     = meta + 410;
  int*   topk_idx   = (int*)take((size_t)T_TOKENS * 2 * 4);
  float* topk_val   = (float*)take((size_t)T_TOKENS * 2 * 4);
  int*   pair_token = (int*)take((size_t)(NPAIR + 256) * 4);
  int*   inv_pos    = (int*)take((size_t)T_TOKENS * 2 * 4);
  u16*   xb         = (u16*)take((size_t)T_TOKENS * D_DIM * 2);
  u16*   w1t        = (u16*)take((size_t)E_NUM * D_DIM * H_DIM * 2);
  u16*   w2t        = (u16*)take((size_t)E_NUM * H_DIM * O_DIM * 2);
  u16*   hbuf       = (u16*)take((size_t)(NPAIR + 128) * H_DIM * 2);
  float* obuf       = (float*)take((size_t)(NPAIR + 128) * O_DIM * 4);

  hipMemsetAsync(meta, 0, 4096, stream);

  transpose_cvt_kernel<<<dim3(H_DIM / 32, D_DIM / 32, E_NUM), dim3(32, 8), 0, stream>>>(w1, w1t, D_DIM, H_DIM);
  transpose_cvt_kernel<<<dim3(O_DIM / 32, H_DIM / 32, E_NUM), dim3(32, 8), 0, stream>>>(w2, w2t, H_DIM, O_DIM);
  gate_kernel<<<T_TOKENS / 4, 256, 0, stream>>>(x, gw, gb, topk_idx, topk_val, xb);
  histscan_kernel<<<1, 256, 0, stream>>>(topk_idx, counts, eoff, nblk, tbl_e, tbl_m0);
  scatter_kernel<<<T_TOKENS / 256, 256, 0, stream>>>(topk_idx, topk_val, eoff, cursor_pad, pair_token, inv_pos);
  gemm1_kernel<<<dim3(16, GY_MAX), 256, 0, stream>>>(xb, w1t, b1, pair_token, eoff, counts, nblk, tbl_e, tbl_m0, hbuf);
  gemm2_kernel<<<dim3(8, GY_MAX), 256, 0, stream>>>(hbuf, w2t, b2, eoff, counts, nblk, tbl_e, tbl_m0, obuf);
  combine_kernel<<<T_TOKENS, 256, 0, stream>>>(obuf, inv_pos, topk_val, out);
}